// Round 15
// baseline (170.494 us; speedup 1.0000x reference)
//
#include <hip/hip_runtime.h>
#include <stdint.h>

#define MAX_RAY 100
#define NBUCK 512          // coarse buckets = top 9 Morton bits
#define PTS_PER_BLK 4096
#define PLACE_CAP 5120     // old-path LDS stage cap
#define CAPB 5120          // staging region capacity per bucket (mean 3906, sigma 62 -> 19 sigma)
typedef unsigned long long ull;
typedef uint32_t u32;

#define N0 262144          // finest cells
#define NBLK0 128          // N0 / 2048
#define NBLKB2 1344        // 1024 + 256 + 64 segid-scan blocks (256 cells each)
#define NTAIL 64           // tail-zero blocks appended to emit grid
#define LKELEMS 272        // per-wave LDS key pool (emit): max(8*34, 4*66, 256)

// ---------- helpers ----------
__device__ __forceinline__ u32 spread1(u32 v) {
    v &= 0x1FF;
    v = (v | (v << 8)) & 0x00FF00FF;
    v = (v | (v << 4)) & 0x0F0F0F0F;
    v = (v | (v << 2)) & 0x33333333;
    v = (v | (v << 1)) & 0x55555555;
    return v;
}
__device__ __forceinline__ u32 morton2(u32 i, u32 j) { return (spread1(i) << 1) | spread1(j); }

__device__ __forceinline__ void px_of(const float2 cv, int& pi, int& pj) {
    float fi = fminf(fmaxf(cv.x * 512.0f, 0.0f), 511.0f);
    float fj = fminf(fmaxf(cv.y * 512.0f, 0.0f), 511.0f);
    pi = (int)fi;   // trunc == floor for non-negative; bit-identical to reference
    pj = (int)fj;
}

// ================= OLD PATH (fallback when ws too small) =================
__global__ __launch_bounds__(256)
void bucket_hist_kernel(const float2* __restrict__ coords,
                        u32* __restrict__ bucketCnt, int n) {
    __shared__ u32 lh[NBUCK];
    int t = threadIdx.x;
    for (int i = t; i < NBUCK; i += 256) lh[i] = 0;
    __syncthreads();
    int base = blockIdx.x * PTS_PER_BLK;
#pragma unroll
    for (int k = 0; k < 16; ++k) {
        int p = base + k * 256 + t;
        if (p < n) {
            int pi, pj; px_of(coords[p], pi, pj);
            atomicAdd(&lh[morton2(pi, pj) >> 9], 1u);
        }
    }
    __syncthreads();
    for (int i = t; i < NBUCK; i += 256)
        if (lh[i]) atomicAdd(&bucketCnt[i], lh[i]);
}

__global__ __launch_bounds__(NBUCK)
void bucket_scan_kernel(const u32* __restrict__ bucketCnt,
                        u32* __restrict__ bucketStart,
                        u32* __restrict__ bucketCur, int n) {
    __shared__ u32 part[NBUCK];
    int t = threadIdx.x;
    u32 v = bucketCnt[t];
    part[t] = v; __syncthreads();
    for (int off = 1; off < NBUCK; off <<= 1) {
        u32 x = part[t]; u32 a = (t >= off) ? part[t - off] : 0u;
        __syncthreads(); part[t] = x + a; __syncthreads();
    }
    u32 ex = part[t] - v;
    bucketStart[t] = ex; bucketCur[t] = ex;
    if (t == NBUCK - 1) bucketStart[NBUCK] = (u32)n;
}

__global__ __launch_bounds__(256)
void bucket_scatter_kernel(const float2* __restrict__ coords,
                           const float* __restrict__ depth,
                           const float* __restrict__ pm,
                           u32* __restrict__ bucketCur,
                           ull* __restrict__ keys,
                           u32* __restrict__ payg,     // may be null
                           int n) {
    __shared__ u32 lhist[NBUCK], lofs[NBUCK], lcur[NBUCK], gbase[NBUCK], temp[256];
    __shared__ ull stage[PTS_PER_BLK];
    int t = threadIdx.x;
    for (int i = t; i < NBUCK; i += 256) lhist[i] = 0;
    __syncthreads();
    int base = blockIdx.x * PTS_PER_BLK;
    ull ent[16]; u32 cb[16]; u32 pos[16];
#pragma unroll
    for (int k = 0; k < 16; ++k) {
        int p = base + k * 256 + t;
        cb[k] = 0xFFFFFFFFu;
        if (p < n) {
            int pi, pj; px_of(coords[p], pi, pj);
            u32 m = morton2(pi, pj);
            cb[k] = m >> 9;
            ent[k] = ((ull)__float_as_uint(depth[p]) << 32)
                   | ((ull)(m & 511u) << 21) | (ull)(u32)p;
            atomicAdd(&lhist[cb[k]], 1u);
        }
    }
    __syncthreads();
    u32 pv = lhist[2 * t] + lhist[2 * t + 1];
    temp[t] = pv; __syncthreads();
    for (int off = 1; off < 256; off <<= 1) {
        u32 x = temp[t]; u32 a = (t >= off) ? temp[t - off] : 0u;
        __syncthreads(); temp[t] = x + a; __syncthreads();
    }
    u32 pb = temp[t] - pv;
    lofs[2 * t] = pb;                  lofs[2 * t + 1] = pb + lhist[2 * t];
    lcur[2 * t] = pb;                  lcur[2 * t + 1] = pb + lhist[2 * t];
    __syncthreads();
#pragma unroll
    for (int k = 0; k < 16; ++k) {
        if (cb[k] != 0xFFFFFFFFu) {
            pos[k] = atomicAdd(&lcur[cb[k]], 1u);
            stage[pos[k]] = ent[k];
        }
    }
    __syncthreads();
    for (int b = t; b < NBUCK; b += 256) {
        u32 cnt = lhist[b];
        if (!cnt) continue;
        u32 gb = atomicAdd(&bucketCur[b], cnt);
        gbase[b] = gb;
        u32 lo = lofs[b];
        for (u32 i = 0; i < cnt; ++i) keys[gb + i] = stage[lo + i];
    }
    if (payg) {
        __syncthreads();
        u32* pstage = (u32*)stage;
#pragma unroll
        for (int k = 0; k < 16; ++k) {
            int p = base + k * 256 + t;
            if (cb[k] != 0xFFFFFFFFu) pstage[pos[k]] = __float_as_uint(pm[p]);
        }
        __syncthreads();
        for (int b = t; b < NBUCK; b += 256) {
            u32 cnt = lhist[b];
            if (!cnt) continue;
            u32 gb = gbase[b], lo = lofs[b];
            for (u32 i = 0; i < cnt; ++i) payg[gb + i] = pstage[lo + i];
        }
    }
}

__global__ __launch_bounds__(256)
void cell_hist_kernel(const ull* __restrict__ keys,
                      const u32* __restrict__ bucketStart,
                      u32* __restrict__ countsM) {
    __shared__ u32 lh[NBUCK];
    int b = blockIdx.x, t = threadIdx.x;
    for (int i = t; i < NBUCK; i += 256) lh[i] = 0;
    __syncthreads();
    u32 s = bucketStart[b], e = bucketStart[b + 1];
    for (u32 i = s + t; i < e; i += 256) {
        u32 mlow = (u32)(keys[i] >> 21) & 511u;
        atomicAdd(&lh[mlow], 1u);
    }
    __syncthreads();
    for (int i = t; i < NBUCK; i += 256) countsM[(b << 9) + i] = lh[i];
}

__global__ __launch_bounds__(256)
void scanA_final2(const u32* __restrict__ countsM,
                  const u32* __restrict__ bucketStart,
                  u32* __restrict__ startsM) {
    int b = blockIdx.x, t = threadIdx.x;
    const uint4* src = (const uint4*)(countsM + b * 2048);
    uint4 a = src[t * 2], c = src[t * 2 + 1];
    u32 e[8] = {a.x, a.y, a.z, a.w, c.x, c.y, c.z, c.w};
    u32 tsum = 0;
#pragma unroll
    for (int k = 0; k < 8; ++k) tsum += e[k];
    __shared__ u32 part[256];
    part[t] = tsum; __syncthreads();
    for (int off = 1; off < 256; off <<= 1) {
        u32 x = part[t];
        u32 ad = (t >= off) ? part[t - off] : 0;
        __syncthreads(); part[t] = x + ad; __syncthreads();
    }
    u32 run = bucketStart[b * 4] + part[t] - tsum;
    u32 o[8];
#pragma unroll
    for (int k = 0; k < 8; ++k) { o[k] = run; run += e[k]; }
    uint4* d1 = (uint4*)(startsM + b * 2048);
    d1[t * 2]     = make_uint4(o[0], o[1], o[2], o[3]);
    d1[t * 2 + 1] = make_uint4(o[4], o[5], o[6], o[7]);
    if (b == NBLK0 - 1 && t == 255) startsM[N0] = run;
}

__global__ __launch_bounds__(256)
void place_kernel(ull* __restrict__ keys,
                  u32* __restrict__ payg,              // may be null
                  const u32* __restrict__ bucketStart,
                  const u32* __restrict__ startsM) {
    __shared__ ull stage[PLACE_CAP];
    __shared__ u32 pstage[PLACE_CAP];
    __shared__ u32 cur[NBUCK];
    int b = blockIdx.x, t = threadIdx.x;
    u32 s = bucketStart[b], e = bucketStart[b + 1];
    u32 cnt = e - s;
    u32 lim = cnt < PLACE_CAP ? cnt : PLACE_CAP;
    for (u32 i = t; i < lim; i += 256) stage[i] = keys[s + i];
    if (payg) for (u32 i = t; i < lim; i += 256) pstage[i] = payg[s + i];
    for (int i = t; i < NBUCK; i += 256) cur[i] = startsM[(b << 9) + i];
    __syncthreads();
    for (u32 i = t; i < lim; i += 256) {
        ull en = stage[i];
        u32 mlow = (u32)(en >> 21) & 511u;
        u32 slot = atomicAdd(&cur[mlow], 1u);
        keys[slot] = ((en >> 32) << 32) | (en & 0x1FFFFFull);
        if (payg) payg[slot] = pstage[i];
    }
}

// ================= NEW PATH: fixed-capacity staging =================
__global__ __launch_bounds__(256)
void bucket_scatter_fixed(const float2* __restrict__ coords,
                          const float* __restrict__ depth,
                          const float* __restrict__ pm,
                          u32* __restrict__ bucketCnt,
                          ull* __restrict__ stageK,
                          u32* __restrict__ stageP,
                          int n) {
    __shared__ u32 lhist[NBUCK], lofs[NBUCK], lcur[NBUCK], gbase[NBUCK], temp[256];
    __shared__ ull stage[PTS_PER_BLK];
    int t = threadIdx.x;
    for (int i = t; i < NBUCK; i += 256) lhist[i] = 0;
    __syncthreads();
    int base = blockIdx.x * PTS_PER_BLK;
    ull ent[16]; u32 cb[16]; u32 pos[16];
#pragma unroll
    for (int k = 0; k < 16; ++k) {
        int p = base + k * 256 + t;
        cb[k] = 0xFFFFFFFFu;
        if (p < n) {
            int pi, pj; px_of(coords[p], pi, pj);
            u32 m = morton2(pi, pj);
            cb[k] = m >> 9;
            ent[k] = ((ull)__float_as_uint(depth[p]) << 32)
                   | ((ull)(m & 511u) << 21) | (ull)(u32)p;
            atomicAdd(&lhist[cb[k]], 1u);
        }
    }
    __syncthreads();
    u32 pv = lhist[2 * t] + lhist[2 * t + 1];
    temp[t] = pv; __syncthreads();
    for (int off = 1; off < 256; off <<= 1) {
        u32 x = temp[t]; u32 a = (t >= off) ? temp[t - off] : 0u;
        __syncthreads(); temp[t] = x + a; __syncthreads();
    }
    u32 pb = temp[t] - pv;
    lofs[2 * t] = pb;                  lofs[2 * t + 1] = pb + lhist[2 * t];
    lcur[2 * t] = pb;                  lcur[2 * t + 1] = pb + lhist[2 * t];
    __syncthreads();
#pragma unroll
    for (int k = 0; k < 16; ++k) {
        if (cb[k] != 0xFFFFFFFFu) {
            pos[k] = atomicAdd(&lcur[cb[k]], 1u);
            stage[pos[k]] = ent[k];
        }
    }
    __syncthreads();
    for (int b = t; b < NBUCK; b += 256) {
        u32 cnt = lhist[b];
        if (!cnt) { gbase[b] = 0xFFFFFFFFu; continue; }
        u32 gb0 = atomicAdd(&bucketCnt[b], cnt);
        gbase[b] = gb0;
        u32 wr = (gb0 >= CAPB) ? 0u : ((cnt < CAPB - gb0) ? cnt : CAPB - gb0);
        u32 gb = b * CAPB + gb0, lo = lofs[b];
        for (u32 i = 0; i < wr; ++i) stageK[gb + i] = stage[lo + i];
    }
    __syncthreads();
    u32* pstage = (u32*)stage;
#pragma unroll
    for (int k = 0; k < 16; ++k) {
        int p = base + k * 256 + t;
        if (cb[k] != 0xFFFFFFFFu) pstage[pos[k]] = __float_as_uint(pm[p]);
    }
    __syncthreads();
    for (int b = t; b < NBUCK; b += 256) {
        u32 cnt = lhist[b], gb0 = gbase[b];
        if (!cnt || gb0 == 0xFFFFFFFFu) continue;
        u32 wr = (gb0 >= CAPB) ? 0u : ((cnt < CAPB - gb0) ? cnt : CAPB - gb0);
        u32 gb = b * CAPB + gb0, lo = lofs[b];
        for (u32 i = 0; i < wr; ++i) stageP[gb + i] = pstage[lo + i];
    }
}

// fused: inline bucket-prefix -> cell-hist -> in-block scan -> startsM -> place.
__global__ __launch_bounds__(256)
void place_fused2(const ull* __restrict__ stageK,
                  const u32* __restrict__ stageP,
                  const u32* __restrict__ bucketCnt,
                  u32* __restrict__ startsM,
                  ull* __restrict__ keysF,
                  u32* __restrict__ payF) {
    __shared__ u32 lh[NBUCK], cur[NBUCK], temp[256];
    __shared__ u32 s_bs;
    int b = blockIdx.x, t = threadIdx.x;
    u32 cnt = bucketCnt[b]; if (cnt > CAPB) cnt = CAPB;
    u32 s = (u32)b * CAPB;
    for (int i = t; i < NBUCK; i += 256) lh[i] = 0;
    __syncthreads();
    for (u32 i = t; i < cnt; i += 256) {
        u32 mlow = (u32)(stageK[s + i] >> 21) & 511u;
        atomicAdd(&lh[mlow], 1u);
    }
    {
        u32 acc = 0;
        for (int i = t; i < b; i += 256) {
            u32 v = bucketCnt[i]; acc += (v > CAPB ? CAPB : v);
        }
        temp[t] = acc; __syncthreads();
        for (int off = 128; off; off >>= 1) {
            if (t < off) temp[t] += temp[t + off];
            __syncthreads();
        }
        if (t == 0) s_bs = temp[0];
        __syncthreads();
    }
    u32 bs = s_bs;
    if (b == NBUCK - 1 && t == 0) startsM[N0] = bs + cnt;
    u32 pv = lh[2 * t] + lh[2 * t + 1];
    temp[t] = pv; __syncthreads();
    for (int off = 1; off < 256; off <<= 1) {
        u32 x = temp[t]; u32 a = (t >= off) ? temp[t - off] : 0u;
        __syncthreads(); temp[t] = x + a; __syncthreads();
    }
    u32 pb = temp[t] - pv;
    u32 st0 = bs + pb, st1 = bs + pb + lh[2 * t];
    cur[2 * t] = st0; cur[2 * t + 1] = st1;
    uint2* d = (uint2*)(startsM + (b << 9));
    d[t] = make_uint2(st0, st1);
    __syncthreads();
    for (u32 i = t; i < cnt; i += 256) {
        ull en = stageK[s + i];
        u32 mlow = (u32)(en >> 21) & 511u;
        u32 slot = atomicAdd(&cur[mlow], 1u);
        keysF[slot] = ((en >> 32) << 32) | (en & 0x1FFFFFull);   // strip mlow
        payF[slot] = stageP[s + i];
    }
}

// ---------- segid scans (256 cells per block, 1 cell/thread) ----------
__device__ __forceinline__ void blk_map2(int b, int& si, int& bb) {
    if (b < 1024)      { si = 0; bb = b; }
    else if (b < 1280) { si = 1; bb = b - 1024; }
    else               { si = 2; bb = b - 1280; }
}
__device__ __forceinline__ u32 cell_cnt(const u32* startsM, int c, int wbits, int si) {
    u32 ci = (u32)c >> wbits, cj = (u32)c & ((1u << wbits) - 1u);
    u32 mb = morton2(ci, cj) << (2 * si);
    return startsM[mb + (1u << (2 * si))] - startsM[mb];
}

__global__ __launch_bounds__(256)
void scanB_partial(const u32* __restrict__ startsM, u32* __restrict__ bsumB) {
    int si, bb; blk_map2(blockIdx.x, si, bb);
    int wbits = 9 - si, t = threadIdx.x;
    int c = bb * 256 + t;
    u32 flg = (cell_cnt(startsM, c, wbits, si) > 0) ? 1u : 0u;
    __shared__ u32 red[256];
    red[t] = flg; __syncthreads();
    for (int off = 128; off; off >>= 1) {
        if (t < off) red[t] += red[t + off];
        __syncthreads();
    }
    if (!t) bsumB[blockIdx.x] = red[0];
}

struct SegArgs {
    u32* segid[3]; float* lens[3]; float* canvas[3];
};
__global__ __launch_bounds__(256)
void scanB_final(const u32* __restrict__ startsM, const u32* __restrict__ bsumB,
                 SegArgs sa, u32* __restrict__ ncells) {
    int si, bb; blk_map2(blockIdx.x, si, bb);
    int wbits = 9 - si, t = threadIdx.x;
    int segStart = (si == 0) ? 0 : (si == 1) ? 1024 : 1280;
    __shared__ u32 s_bpre;
    if (t < 64) {
        u32 acc = 0;
        for (int j = segStart + t; j < (int)blockIdx.x; j += 64) acc += bsumB[j];
        for (int o = 32; o; o >>= 1) acc += __shfl_down(acc, o);
        if (t == 0) s_bpre = acc;
    }
    int c = bb * 256 + t;
    u32 cnt = cell_cnt(startsM, c, wbits, si);
    u32 flg = cnt ? 1u : 0u;
    __shared__ u32 part[256];
    part[t] = flg; __syncthreads();
    for (int off = 1; off < 256; off <<= 1) {
        u32 x = part[t];
        u32 ad = (t >= off) ? part[t - off] : 0u;
        __syncthreads(); part[t] = x + ad; __syncthreads();
    }
    u32 run = s_bpre + part[t] - flg;
    u32* segid = sa.segid[si];
    float* lens = sa.lens[si];
    float* canvas = sa.canvas[si];
    u32 wmask = (1u << wbits) - 1u;
    segid[c] = run;
    if (flg) {
        u32 len = cnt < MAX_RAY ? cnt : MAX_RAY;
        lens[run] = (float)len;
        canvas[2 * run]     = (float)((u32)c >> wbits);
        canvas[2 * run + 1] = (float)((u32)c & wmask);
    }
    if (t == 255 && (blockIdx.x == 1023 || blockIdx.x == 1279 || blockIdx.x == 1343))
        ncells[si] = run + flg;
}

// ---------- emit: 512-thread (8-wave) grouped LDS-broadcast rank + fused tail ----------
struct CellRegs { ull k0, k1, k2, k3; u32 p0, p1, p2, p3; };
struct __attribute__((packed, aligned(8))) U2 { ull x, y; };
struct __attribute__((packed, aligned(4))) U4 { u32 x, y, z, w; };

template<int CAP>
__device__ __forceinline__ void loadCellG(const ull* __restrict__ keys,
                                          const u32* __restrict__ payg,
                                          const float* __restrict__ pm,
                                          u32 s0, u32 cnt, u32 li, CellRegs& c) {
    c.k0 = c.k1 = c.k2 = c.k3 = ~0ull;
    c.p0 = c.p1 = c.p2 = c.p3 = 0u;
    u32 m = li * 4u;
    if (cnt == 0u || cnt > (u32)CAP || m >= cnt) return;
    const U2* kp = (const U2*)(keys + s0 + m);
    U2 a = kp[0], b = kp[1];
    c.k0 = a.x; c.k1 = a.y; c.k2 = b.x; c.k3 = b.y;
    if (payg) {
        U4 pv = *(const U4*)(payg + s0 + m);
        c.p0 = pv.x; c.p1 = pv.y; c.p2 = pv.z; c.p3 = pv.w;
    } else {
        c.p0 = __float_as_uint(pm[(u32)(c.k0 & 0x1FFFFFull)]);
        if (m + 1 < cnt) c.p1 = __float_as_uint(pm[(u32)(c.k1 & 0x1FFFFFull)]);
        if (m + 2 < cnt) c.p2 = __float_as_uint(pm[(u32)(c.k2 & 0x1FFFFFull)]);
        if (m + 3 < cnt) c.p3 = __float_as_uint(pm[(u32)(c.k3 & 0x1FFFFFull)]);
    }
    if (m + 1 >= cnt) c.k1 = ~0ull;
    if (m + 2 >= cnt) c.k2 = ~0ull;
    if (m + 3 >= cnt) c.k3 = ~0ull;
}

template<int SI>
__device__ __forceinline__ void emit_body(
    const float* __restrict__ pm, const u32* __restrict__ payload,
    const u32* __restrict__ startsM, const ull* __restrict__ keys,
    const u32* __restrict__ segid, float* __restrict__ batch, int bb,
    float (&tile)[64][101], ull (&lkAll)[8][LKELEMS],
    u32 (&s_s0)[64], u32 (&s_cnt)[64], u32 (&s_seg)[64],
    u32 (&ovfl)[64], u32& ovflN)
{
    constexpr int WB   = 9 - SI;
    constexpr int G    = (SI == 0) ? 8 : (SI == 1) ? 16 : 64;    // lanes per cell
    constexpr int CAP  = G * 4;                                   // 32 / 64 / 256
    constexpr int STRD = (SI == 0) ? 34 : (SI == 1) ? 66 : 256;   // padded stride
    constexpr int NG   = 64 / G;                                  // groups per wave
    constexpr int ROUNDS = 64 / (8 * NG);                         // 1 / 2 / 8
    const int HW = 1 << (2 * WB);

    int t = threadIdx.x, wave = t >> 6, lane = t & 63;
    int gi = lane / G, li = lane % G;
    ull* lk = &lkAll[wave][0];

    if (t == 0) ovflN = 0;
    if (t < 64) {
        int cell = bb * 64 + t;
        u32 ci = (u32)cell >> WB, cj = (u32)cell & ((1u << WB) - 1u);
        u32 mb = morton2(ci, cj) << (2 * SI);
        u32 s0 = startsM[mb];
        s_s0[t]  = s0;
        s_cnt[t] = startsM[mb + (1u << (2 * SI))] - s0;
        s_seg[t] = segid[cell];
    }
    __syncthreads();

    CellRegs cur, nxt;
    {
        int lc0 = wave * NG + gi;
        loadCellG<CAP>(keys, payload, pm, s_s0[lc0], s_cnt[lc0], (u32)li, cur);
    }
#pragma unroll
    for (int rnd = 0; rnd < ROUNDS; ++rnd) {
        int lc = (rnd * 8 + wave) * NG + gi;
        u32 cnt = s_cnt[lc], m = (u32)li * 4u;
        bool fits = (cnt <= (u32)CAP);
        if (fits && m < cnt) {
            ull* dst = lk + gi * STRD + m;
            dst[0] = cur.k0; dst[1] = cur.k1; dst[2] = cur.k2; dst[3] = cur.k3;
        }
        if (!fits && li == 0) {
            u32 ix = atomicAdd(&ovflN, 1u);
            ovfl[ix] = (u32)lc;
        }
        if (rnd + 1 < ROUNDS) {
            int lc2 = ((rnd + 1) * 8 + wave) * NG + gi;
            loadCellG<CAP>(keys, payload, pm, s_s0[lc2], s_cnt[lc2], (u32)li, nxt);
        }
        if (cnt && fits) {
            asm volatile("s_waitcnt lgkmcnt(0)" ::: "memory");
            u32 cntR = (cnt + 3u) & ~3u;
            u32 r0 = 0, r1 = 0, r2 = 0, r3 = 0;
            const ull* kb = lk + gi * STRD;
            for (u32 j = 0; j < cntR; j += 4) {
                U2 a  = *(const U2*)(kb + j);
                U2 b2 = *(const U2*)(kb + j + 2);
                r0 += (a.x < cur.k0) + (a.y < cur.k0) + (b2.x < cur.k0) + (b2.y < cur.k0);
                r1 += (a.x < cur.k1) + (a.y < cur.k1) + (b2.x < cur.k1) + (b2.y < cur.k1);
                r2 += (a.x < cur.k2) + (a.y < cur.k2) + (b2.x < cur.k2) + (b2.y < cur.k2);
                r3 += (a.x < cur.k3) + (a.y < cur.k3) + (b2.x < cur.k3) + (b2.y < cur.k3);
            }
            if (m < cnt) {
                if (r0 < MAX_RAY)                 tile[lc][r0] = __uint_as_float(cur.p0);
                if (m + 1 < cnt && r1 < MAX_RAY)  tile[lc][r1] = __uint_as_float(cur.p1);
                if (m + 2 < cnt && r2 < MAX_RAY)  tile[lc][r2] = __uint_as_float(cur.p2);
                if (m + 3 < cnt && r3 < MAX_RAY)  tile[lc][r3] = __uint_as_float(cur.p3);
            }
        }
        cur = nxt;
    }
    __syncthreads();

    u32 no = ovflN;
    if (no && wave == 0) {
        for (u32 o = 0; o < no; ++o) {
            int lc = (int)ovfl[o];
            u32 s0 = s_s0[lc], cnt = s_cnt[lc];
            for (u32 i = lane; i < cnt; i += 64) {
                ull mk = keys[s0 + i];
                u32 r = 0;
                for (u32 j = 0; j < cnt; ++j) r += (keys[s0 + j] < mk) ? 1u : 0u;
                if (r < MAX_RAY) {
                    u32 pv = payload ? payload[s0 + i]
                                     : __float_as_uint(pm[(u32)(mk & 0x1FFFFFull)]);
                    tile[lc][r] = __uint_as_float(pv);
                }
            }
        }
    }
    __syncthreads();

    u32 myCnt = s_cnt[lane], mySeg = s_seg[lane];
    u32 lim = myCnt < MAX_RAY ? myCnt : MAX_RAY;
    for (int r = wave; r < MAX_RAY; r += 8) {
        if (myCnt) batch[(size_t)r * (size_t)HW + mySeg] = (r < (int)lim) ? tile[lane][r] : 0.0f;
    }
}

struct EmitArgs {
    const u32* segid[3]; float* batch[3]; float* lens[3]; float* canvas[3];
};
__global__ __launch_bounds__(512)
void emit_kernel(const float* __restrict__ pm,
                 const u32* __restrict__ payload,
                 const u32* __restrict__ startsM,
                 const ull* __restrict__ keys,
                 EmitArgs ea,
                 const u32* __restrict__ ncells) {
    __shared__ float tile[64][101];
    __shared__ __align__(16) ull lkAll[8][LKELEMS];
    __shared__ u32 s_s0[64], s_cnt[64], s_seg[64], ovfl[64], ovflN;

    int b = blockIdx.x;
    if (b >= 5376) {                       // fused tail-zero blocks
        int tb = b - 5376, t = threadIdx.x;
        for (int si = 0; si < 3; ++si) {
            int HW = (si == 0) ? 262144 : (si == 1) ? 65536 : 16384;
            float* batch = ea.batch[si];
            float* lens = ea.lens[si];
            float* canv = ea.canvas[si];
            u32 nc = ncells[si];
            for (u32 col = nc + (u32)(tb * 512 + t); col < (u32)HW; col += NTAIL * 512) {
                lens[col] = 0.0f;
                canv[2 * col] = 0.0f; canv[2 * col + 1] = 0.0f;
                for (int r = 0; r < MAX_RAY; ++r)
                    batch[(size_t)r * (size_t)HW + col] = 0.0f;
            }
        }
        return;
    }
    if (b < 256)
        emit_body<2>(pm, payload, startsM, keys, ea.segid[2], ea.batch[2], b,
                     tile, lkAll, s_s0, s_cnt, s_seg, ovfl, ovflN);
    else if (b < 1280)
        emit_body<1>(pm, payload, startsM, keys, ea.segid[1], ea.batch[1], b - 256,
                     tile, lkAll, s_s0, s_cnt, s_seg, ovfl, ovflN);
    else
        emit_body<0>(pm, payload, startsM, keys, ea.segid[0], ea.batch[0], b - 1280,
                     tile, lkAll, s_s0, s_cnt, s_seg, ovfl, ovflN);
}

extern "C" void kernel_launch(void* const* d_in, const int* in_sizes, int n_in,
                              void* d_out, int out_size, void* d_ws, size_t ws_size,
                              hipStream_t stream) {
    const float2* coords = (const float2*)d_in[0];
    const float*  depth  = (const float*)d_in[1];
    const float*  pm     = (const float*)d_in[2];
    float* out = (float*)d_out;
    const int n = in_sizes[1];

    const int HWs[3] = {512 * 512, 256 * 256, 128 * 128};

    // ---- workspace layout ----
    char* ws = (char*)d_ws;
    size_t off = 0;
    ull* keysF   = (ull*)(ws + off); off += (size_t)n * 8;
    u32* countsM = (u32*)(ws + off); off += (size_t)N0 * 4;
    u32* startsM = (u32*)(ws + off); off += (size_t)(N0 + 64) * 4;
    u32* segid[3];
    for (int i = 0; i < 3; ++i) { segid[i] = (u32*)(ws + off); off += (size_t)HWs[i] * 4; }
    u32* bsumB = (u32*)(ws + off); off += 2048 * 4;
    u32* bucketCnt   = (u32*)(ws + off); off += NBUCK * 4;
    u32* bucketStart = (u32*)(ws + off); off += (NBUCK + 64) * 4;
    u32* bucketCur   = (u32*)(ws + off); off += NBUCK * 4;
    u32* ncells      = (u32*)(ws + off); off += 64 * 4;
    u32* payF        = (u32*)(ws + off);
    size_t needPay = off + (size_t)n * 4;
    size_t offStage = needPay;
    ull* stageK = (ull*)(ws + offStage);
    u32* stageP = (u32*)(ws + offStage + (size_t)NBUCK * CAPB * 8);
    size_t needStaged = offStage + (size_t)NBUCK * CAPB * 12;

    bool haveStage = (ws_size >= needStaged);
    u32* payg = (ws_size >= needPay) ? payF : nullptr;

    // ---- output offsets ----
    size_t offB[3], offL[3], offC[3];
    size_t o = 0;
    for (int i = 0; i < 3; ++i) { offB[i] = o; o += (size_t)MAX_RAY * HWs[i]; }
    for (int i = 0; i < 3; ++i) { offL[i] = o; o += (size_t)HWs[i]; }
    for (int i = 0; i < 3; ++i) { offC[i] = o; o += 2 * (size_t)HWs[i]; }

    hipMemsetAsync(bucketCnt, 0, NBUCK * 4, stream);

    const int nblkPts = (n + PTS_PER_BLK - 1) / PTS_PER_BLK;

    if (haveStage) {
        bucket_scatter_fixed<<<nblkPts, 256, 0, stream>>>(coords, depth, pm, bucketCnt,
                                                          stageK, stageP, n);
        place_fused2<<<NBUCK, 256, 0, stream>>>(stageK, stageP, bucketCnt,
                                                startsM, keysF, payF);
        payg = payF;
    } else {
        bucket_hist_kernel<<<nblkPts, 256, 0, stream>>>(coords, bucketCnt, n);
        bucket_scan_kernel<<<1, NBUCK, 0, stream>>>(bucketCnt, bucketStart, bucketCur, n);
        bucket_scatter_kernel<<<nblkPts, 256, 0, stream>>>(coords, depth, pm, bucketCur,
                                                           keysF, payg, n);
        cell_hist_kernel<<<NBUCK, 256, 0, stream>>>(keysF, bucketStart, countsM);
        scanA_final2<<<NBLK0, 256, 0, stream>>>(countsM, bucketStart, startsM);
        place_kernel<<<NBUCK, 256, 0, stream>>>(keysF, payg, bucketStart, startsM);
    }

    SegArgs sa;
    for (int i = 0; i < 3; ++i) {
        sa.segid[i]  = segid[i];
        sa.lens[i]   = out + offL[i];
        sa.canvas[i] = out + offC[i];
    }
    scanB_partial<<<NBLKB2, 256, 0, stream>>>(startsM, bsumB);
    scanB_final<<<NBLKB2, 256, 0, stream>>>(startsM, bsumB, sa, ncells);

    EmitArgs ea;
    for (int i = 0; i < 3; ++i) {
        ea.segid[i]  = segid[i];
        ea.batch[i]  = out + offB[i];
        ea.lens[i]   = out + offL[i];
        ea.canvas[i] = out + offC[i];
    }
    emit_kernel<<<5376 + NTAIL, 512, 0, stream>>>(pm, payg, startsM, keysF, ea, ncells);
}

// Round 16
// 166.570 us; speedup vs baseline: 1.0236x; 1.0236x over previous
//
#include <hip/hip_runtime.h>
#include <stdint.h>

#define MAX_RAY 100
#define NBUCK 512          // coarse buckets = top 9 Morton bits
#define PTS_PER_BLK 4096
#define PLACE_CAP 5120     // old-path LDS stage cap
#define CAPB 5120          // staging region capacity per bucket (mean 3906, sigma 62 -> 19 sigma)
typedef unsigned long long ull;
typedef uint32_t u32;

#define N0 262144          // finest cells
#define NBLK0 128          // N0 / 2048
#define NBLKB2 1344        // 1024 + 256 + 64 segid-scan blocks (256 cells each)
#define NTAIL 64           // tail-zero blocks appended to emit grid
#define LKELEMS 288        // per-wave LDS key pool (emit)

// ---------- helpers ----------
__device__ __forceinline__ u32 spread1(u32 v) {
    v &= 0x1FF;
    v = (v | (v << 8)) & 0x00FF00FF;
    v = (v | (v << 4)) & 0x0F0F0F0F;
    v = (v | (v << 2)) & 0x33333333;
    v = (v | (v << 1)) & 0x55555555;
    return v;
}
__device__ __forceinline__ u32 morton2(u32 i, u32 j) { return (spread1(i) << 1) | spread1(j); }

__device__ __forceinline__ void px_of(const float2 cv, int& pi, int& pj) {
    float fi = fminf(fmaxf(cv.x * 512.0f, 0.0f), 511.0f);
    float fj = fminf(fmaxf(cv.y * 512.0f, 0.0f), 511.0f);
    pi = (int)fi;   // trunc == floor for non-negative; bit-identical to reference
    pj = (int)fj;
}

// ================= OLD PATH (fallback when ws too small) =================
__global__ __launch_bounds__(256)
void bucket_hist_kernel(const float2* __restrict__ coords,
                        u32* __restrict__ bucketCnt, int n) {
    __shared__ u32 lh[NBUCK];
    int t = threadIdx.x;
    for (int i = t; i < NBUCK; i += 256) lh[i] = 0;
    __syncthreads();
    int base = blockIdx.x * PTS_PER_BLK;
#pragma unroll
    for (int k = 0; k < 16; ++k) {
        int p = base + k * 256 + t;
        if (p < n) {
            int pi, pj; px_of(coords[p], pi, pj);
            atomicAdd(&lh[morton2(pi, pj) >> 9], 1u);
        }
    }
    __syncthreads();
    for (int i = t; i < NBUCK; i += 256)
        if (lh[i]) atomicAdd(&bucketCnt[i], lh[i]);
}

__global__ __launch_bounds__(NBUCK)
void bucket_scan_kernel(const u32* __restrict__ bucketCnt,
                        u32* __restrict__ bucketStart,
                        u32* __restrict__ bucketCur, int n) {
    __shared__ u32 part[NBUCK];
    int t = threadIdx.x;
    u32 v = bucketCnt[t];
    part[t] = v; __syncthreads();
    for (int off = 1; off < NBUCK; off <<= 1) {
        u32 x = part[t]; u32 a = (t >= off) ? part[t - off] : 0u;
        __syncthreads(); part[t] = x + a; __syncthreads();
    }
    u32 ex = part[t] - v;
    bucketStart[t] = ex; bucketCur[t] = ex;
    if (t == NBUCK - 1) bucketStart[NBUCK] = (u32)n;
}

__global__ __launch_bounds__(256)
void bucket_scatter_kernel(const float2* __restrict__ coords,
                           const float* __restrict__ depth,
                           const float* __restrict__ pm,
                           u32* __restrict__ bucketCur,
                           ull* __restrict__ keys,
                           u32* __restrict__ payg,     // may be null
                           int n) {
    __shared__ u32 lhist[NBUCK], lofs[NBUCK], lcur[NBUCK], gbase[NBUCK], temp[256];
    __shared__ ull stage[PTS_PER_BLK];
    int t = threadIdx.x;
    for (int i = t; i < NBUCK; i += 256) lhist[i] = 0;
    __syncthreads();
    int base = blockIdx.x * PTS_PER_BLK;
    ull ent[16]; u32 cb[16]; u32 pos[16];
#pragma unroll
    for (int k = 0; k < 16; ++k) {
        int p = base + k * 256 + t;
        cb[k] = 0xFFFFFFFFu;
        if (p < n) {
            int pi, pj; px_of(coords[p], pi, pj);
            u32 m = morton2(pi, pj);
            cb[k] = m >> 9;
            ent[k] = ((ull)__float_as_uint(depth[p]) << 32)
                   | ((ull)(m & 511u) << 21) | (ull)(u32)p;
            atomicAdd(&lhist[cb[k]], 1u);
        }
    }
    __syncthreads();
    u32 pv = lhist[2 * t] + lhist[2 * t + 1];
    temp[t] = pv; __syncthreads();
    for (int off = 1; off < 256; off <<= 1) {
        u32 x = temp[t]; u32 a = (t >= off) ? temp[t - off] : 0u;
        __syncthreads(); temp[t] = x + a; __syncthreads();
    }
    u32 pb = temp[t] - pv;
    lofs[2 * t] = pb;                  lofs[2 * t + 1] = pb + lhist[2 * t];
    lcur[2 * t] = pb;                  lcur[2 * t + 1] = pb + lhist[2 * t];
    __syncthreads();
#pragma unroll
    for (int k = 0; k < 16; ++k) {
        if (cb[k] != 0xFFFFFFFFu) {
            pos[k] = atomicAdd(&lcur[cb[k]], 1u);
            stage[pos[k]] = ent[k];
        }
    }
    __syncthreads();
    for (int b = t; b < NBUCK; b += 256) {
        u32 cnt = lhist[b];
        if (!cnt) continue;
        u32 gb = atomicAdd(&bucketCur[b], cnt);
        gbase[b] = gb;
        u32 lo = lofs[b];
        for (u32 i = 0; i < cnt; ++i) keys[gb + i] = stage[lo + i];
    }
    if (payg) {
        __syncthreads();
        u32* pstage = (u32*)stage;
#pragma unroll
        for (int k = 0; k < 16; ++k) {
            int p = base + k * 256 + t;
            if (cb[k] != 0xFFFFFFFFu) pstage[pos[k]] = __float_as_uint(pm[p]);
        }
        __syncthreads();
        for (int b = t; b < NBUCK; b += 256) {
            u32 cnt = lhist[b];
            if (!cnt) continue;
            u32 gb = gbase[b], lo = lofs[b];
            for (u32 i = 0; i < cnt; ++i) payg[gb + i] = pstage[lo + i];
        }
    }
}

__global__ __launch_bounds__(256)
void cell_hist_kernel(const ull* __restrict__ keys,
                      const u32* __restrict__ bucketStart,
                      u32* __restrict__ countsM) {
    __shared__ u32 lh[NBUCK];
    int b = blockIdx.x, t = threadIdx.x;
    for (int i = t; i < NBUCK; i += 256) lh[i] = 0;
    __syncthreads();
    u32 s = bucketStart[b], e = bucketStart[b + 1];
    for (u32 i = s + t; i < e; i += 256) {
        u32 mlow = (u32)(keys[i] >> 21) & 511u;
        atomicAdd(&lh[mlow], 1u);
    }
    __syncthreads();
    for (int i = t; i < NBUCK; i += 256) countsM[(b << 9) + i] = lh[i];
}

__global__ __launch_bounds__(256)
void scanA_final2(const u32* __restrict__ countsM,
                  const u32* __restrict__ bucketStart,
                  u32* __restrict__ startsM) {
    int b = blockIdx.x, t = threadIdx.x;
    const uint4* src = (const uint4*)(countsM + b * 2048);
    uint4 a = src[t * 2], c = src[t * 2 + 1];
    u32 e[8] = {a.x, a.y, a.z, a.w, c.x, c.y, c.z, c.w};
    u32 tsum = 0;
#pragma unroll
    for (int k = 0; k < 8; ++k) tsum += e[k];
    __shared__ u32 part[256];
    part[t] = tsum; __syncthreads();
    for (int off = 1; off < 256; off <<= 1) {
        u32 x = part[t];
        u32 ad = (t >= off) ? part[t - off] : 0;
        __syncthreads(); part[t] = x + ad; __syncthreads();
    }
    u32 run = bucketStart[b * 4] + part[t] - tsum;
    u32 o[8];
#pragma unroll
    for (int k = 0; k < 8; ++k) { o[k] = run; run += e[k]; }
    uint4* d1 = (uint4*)(startsM + b * 2048);
    d1[t * 2]     = make_uint4(o[0], o[1], o[2], o[3]);
    d1[t * 2 + 1] = make_uint4(o[4], o[5], o[6], o[7]);
    if (b == NBLK0 - 1 && t == 255) startsM[N0] = run;
}

__global__ __launch_bounds__(256)
void place_kernel(ull* __restrict__ keys,
                  u32* __restrict__ payg,              // may be null
                  const u32* __restrict__ bucketStart,
                  const u32* __restrict__ startsM) {
    __shared__ ull stage[PLACE_CAP];
    __shared__ u32 pstage[PLACE_CAP];
    __shared__ u32 cur[NBUCK];
    int b = blockIdx.x, t = threadIdx.x;
    u32 s = bucketStart[b], e = bucketStart[b + 1];
    u32 cnt = e - s;
    u32 lim = cnt < PLACE_CAP ? cnt : PLACE_CAP;
    for (u32 i = t; i < lim; i += 256) stage[i] = keys[s + i];
    if (payg) for (u32 i = t; i < lim; i += 256) pstage[i] = payg[s + i];
    for (int i = t; i < NBUCK; i += 256) cur[i] = startsM[(b << 9) + i];
    __syncthreads();
    for (u32 i = t; i < lim; i += 256) {
        ull en = stage[i];
        u32 mlow = (u32)(en >> 21) & 511u;
        u32 slot = atomicAdd(&cur[mlow], 1u);
        keys[slot] = ((en >> 32) << 32) | (en & 0x1FFFFFull);
        if (payg) payg[slot] = pstage[i];
    }
}

// ================= NEW PATH: fixed-capacity staging =================
__global__ __launch_bounds__(256)
void bucket_scatter_fixed(const float2* __restrict__ coords,
                          const float* __restrict__ depth,
                          const float* __restrict__ pm,
                          u32* __restrict__ bucketCnt,
                          ull* __restrict__ stageK,
                          u32* __restrict__ stageP,
                          int n) {
    __shared__ u32 lhist[NBUCK], lofs[NBUCK], lcur[NBUCK], gbase[NBUCK], temp[256];
    __shared__ ull stage[PTS_PER_BLK];
    int t = threadIdx.x;
    for (int i = t; i < NBUCK; i += 256) lhist[i] = 0;
    __syncthreads();
    int base = blockIdx.x * PTS_PER_BLK;
    ull ent[16]; u32 cb[16]; u32 pos[16];
#pragma unroll
    for (int k = 0; k < 16; ++k) {
        int p = base + k * 256 + t;
        cb[k] = 0xFFFFFFFFu;
        if (p < n) {
            int pi, pj; px_of(coords[p], pi, pj);
            u32 m = morton2(pi, pj);
            cb[k] = m >> 9;
            ent[k] = ((ull)__float_as_uint(depth[p]) << 32)
                   | ((ull)(m & 511u) << 21) | (ull)(u32)p;
            atomicAdd(&lhist[cb[k]], 1u);
        }
    }
    __syncthreads();
    u32 pv = lhist[2 * t] + lhist[2 * t + 1];
    temp[t] = pv; __syncthreads();
    for (int off = 1; off < 256; off <<= 1) {
        u32 x = temp[t]; u32 a = (t >= off) ? temp[t - off] : 0u;
        __syncthreads(); temp[t] = x + a; __syncthreads();
    }
    u32 pb = temp[t] - pv;
    lofs[2 * t] = pb;                  lofs[2 * t + 1] = pb + lhist[2 * t];
    lcur[2 * t] = pb;                  lcur[2 * t + 1] = pb + lhist[2 * t];
    __syncthreads();
#pragma unroll
    for (int k = 0; k < 16; ++k) {
        if (cb[k] != 0xFFFFFFFFu) {
            pos[k] = atomicAdd(&lcur[cb[k]], 1u);
            stage[pos[k]] = ent[k];
        }
    }
    __syncthreads();
    for (int b = t; b < NBUCK; b += 256) {
        u32 cnt = lhist[b];
        if (!cnt) { gbase[b] = 0xFFFFFFFFu; continue; }
        u32 gb0 = atomicAdd(&bucketCnt[b], cnt);
        gbase[b] = gb0;
        u32 wr = (gb0 >= CAPB) ? 0u : ((cnt < CAPB - gb0) ? cnt : CAPB - gb0);
        u32 gb = b * CAPB + gb0, lo = lofs[b];
        for (u32 i = 0; i < wr; ++i) stageK[gb + i] = stage[lo + i];
    }
    __syncthreads();
    u32* pstage = (u32*)stage;
#pragma unroll
    for (int k = 0; k < 16; ++k) {
        int p = base + k * 256 + t;
        if (cb[k] != 0xFFFFFFFFu) pstage[pos[k]] = __float_as_uint(pm[p]);
    }
    __syncthreads();
    for (int b = t; b < NBUCK; b += 256) {
        u32 cnt = lhist[b], gb0 = gbase[b];
        if (!cnt || gb0 == 0xFFFFFFFFu) continue;
        u32 wr = (gb0 >= CAPB) ? 0u : ((cnt < CAPB - gb0) ? cnt : CAPB - gb0);
        u32 gb = b * CAPB + gb0, lo = lofs[b];
        for (u32 i = 0; i < wr; ++i) stageP[gb + i] = pstage[lo + i];
    }
}

// fused: inline bucket-prefix -> cell-hist -> in-block scan -> startsM -> place.
// (no bucket_scan2 dispatch; block 511 writes the startsM[N0] sentinel)
__global__ __launch_bounds__(256)
void place_fused2(const ull* __restrict__ stageK,
                  const u32* __restrict__ stageP,
                  const u32* __restrict__ bucketCnt,
                  u32* __restrict__ startsM,
                  ull* __restrict__ keysF,
                  u32* __restrict__ payF) {
    __shared__ u32 lh[NBUCK], cur[NBUCK], temp[256];
    __shared__ u32 s_bs;
    int b = blockIdx.x, t = threadIdx.x;
    u32 cnt = bucketCnt[b]; if (cnt > CAPB) cnt = CAPB;
    u32 s = (u32)b * CAPB;
    for (int i = t; i < NBUCK; i += 256) lh[i] = 0;
    __syncthreads();
    // phase 1: cell histogram of this bucket
    for (u32 i = t; i < cnt; i += 256) {
        u32 mlow = (u32)(stageK[s + i] >> 21) & 511u;
        atomicAdd(&lh[mlow], 1u);
    }
    // phase 1b (overlapped): bucket prefix bs = sum_{i<b} min(bucketCnt[i],CAPB)
    {
        u32 acc = 0;
        for (int i = t; i < b; i += 256) {
            u32 v = bucketCnt[i]; acc += (v > CAPB ? CAPB : v);
        }
        temp[t] = acc; __syncthreads();          // also fences the lh atomics
        for (int off = 128; off; off >>= 1) {
            if (t < off) temp[t] += temp[t + off];
            __syncthreads();
        }
        if (t == 0) s_bs = temp[0];
        __syncthreads();
    }
    u32 bs = s_bs;
    if (b == NBUCK - 1 && t == 0) startsM[N0] = bs + cnt;   // sentinel = total
    // phase 2: scan 512 cell counts (pair trick); write startsM slice
    u32 pv = lh[2 * t] + lh[2 * t + 1];
    temp[t] = pv; __syncthreads();
    for (int off = 1; off < 256; off <<= 1) {
        u32 x = temp[t]; u32 a = (t >= off) ? temp[t - off] : 0u;
        __syncthreads(); temp[t] = x + a; __syncthreads();
    }
    u32 pb = temp[t] - pv;
    u32 st0 = bs + pb, st1 = bs + pb + lh[2 * t];
    cur[2 * t] = st0; cur[2 * t + 1] = st1;
    uint2* d = (uint2*)(startsM + (b << 9));
    d[t] = make_uint2(st0, st1);
    __syncthreads();
    // phase 3: place into exact cell slots (strip mlow: key = depth<<32 | idx)
    for (u32 i = t; i < cnt; i += 256) {
        ull en = stageK[s + i];
        u32 mlow = (u32)(en >> 21) & 511u;
        u32 slot = atomicAdd(&cur[mlow], 1u);
        keysF[slot] = ((en >> 32) << 32) | (en & 0x1FFFFFull);
        payF[slot] = stageP[s + i];
    }
}

// ---------- segid scans (256 cells per block, 1 cell/thread) ----------
__device__ __forceinline__ void blk_map2(int b, int& si, int& bb) {
    if (b < 1024)      { si = 0; bb = b; }
    else if (b < 1280) { si = 1; bb = b - 1024; }
    else               { si = 2; bb = b - 1280; }
}
__device__ __forceinline__ u32 cell_cnt(const u32* startsM, int c, int wbits, int si) {
    u32 ci = (u32)c >> wbits, cj = (u32)c & ((1u << wbits) - 1u);
    u32 mb = morton2(ci, cj) << (2 * si);
    return startsM[mb + (1u << (2 * si))] - startsM[mb];
}

__global__ __launch_bounds__(256)
void scanB_partial(const u32* __restrict__ startsM, u32* __restrict__ bsumB) {
    int si, bb; blk_map2(blockIdx.x, si, bb);
    int wbits = 9 - si, t = threadIdx.x;
    int c = bb * 256 + t;
    u32 flg = (cell_cnt(startsM, c, wbits, si) > 0) ? 1u : 0u;
    __shared__ u32 red[256];
    red[t] = flg; __syncthreads();
    for (int off = 128; off; off >>= 1) {
        if (t < off) red[t] += red[t + off];
        __syncthreads();
    }
    if (!t) bsumB[blockIdx.x] = red[0];
}

struct SegArgs {
    u32* segid[3]; float* lens[3]; float* canvas[3];
};
__global__ __launch_bounds__(256)
void scanB_final(const u32* __restrict__ startsM, const u32* __restrict__ bsumB,
                 SegArgs sa, u32* __restrict__ ncells) {
    int si, bb; blk_map2(blockIdx.x, si, bb);
    int wbits = 9 - si, t = threadIdx.x;
    int segStart = (si == 0) ? 0 : (si == 1) ? 1024 : 1280;
    __shared__ u32 s_bpre;
    if (t < 64) {
        u32 acc = 0;
        for (int j = segStart + t; j < (int)blockIdx.x; j += 64) acc += bsumB[j];
        for (int o = 32; o; o >>= 1) acc += __shfl_down(acc, o);
        if (t == 0) s_bpre = acc;
    }
    int c = bb * 256 + t;
    u32 cnt = cell_cnt(startsM, c, wbits, si);
    u32 flg = cnt ? 1u : 0u;
    __shared__ u32 part[256];
    part[t] = flg; __syncthreads();
    for (int off = 1; off < 256; off <<= 1) {
        u32 x = part[t];
        u32 ad = (t >= off) ? part[t - off] : 0u;
        __syncthreads(); part[t] = x + ad; __syncthreads();
    }
    u32 run = s_bpre + part[t] - flg;
    u32* segid = sa.segid[si];
    float* lens = sa.lens[si];
    float* canvas = sa.canvas[si];
    u32 wmask = (1u << wbits) - 1u;
    segid[c] = run;
    if (flg) {
        u32 len = cnt < MAX_RAY ? cnt : MAX_RAY;
        lens[run] = (float)len;
        canvas[2 * run]     = (float)((u32)c >> wbits);
        canvas[2 * run + 1] = (float)((u32)c & wmask);
    }
    if (t == 255 && (blockIdx.x == 1023 || blockIdx.x == 1279 || blockIdx.x == 1343))
        ncells[si] = run + flg;
}

// ---------- emit: grouped LDS-broadcast rank + fused tail-zero ----------
struct CellRegs { ull k0, k1, k2, k3; u32 p0, p1, p2, p3; };
struct __attribute__((packed, aligned(8))) U2 { ull x, y; };
struct __attribute__((packed, aligned(4))) U4 { u32 x, y, z, w; };

template<int CAP>
__device__ __forceinline__ void loadCellG(const ull* __restrict__ keys,
                                          const u32* __restrict__ payg,
                                          const float* __restrict__ pm,
                                          u32 s0, u32 cnt, u32 li, CellRegs& c) {
    c.k0 = c.k1 = c.k2 = c.k3 = ~0ull;
    c.p0 = c.p1 = c.p2 = c.p3 = 0u;
    u32 m = li * 4u;
    if (cnt == 0u || cnt > (u32)CAP || m >= cnt) return;
    const U2* kp = (const U2*)(keys + s0 + m);
    U2 a = kp[0], b = kp[1];
    c.k0 = a.x; c.k1 = a.y; c.k2 = b.x; c.k3 = b.y;
    if (payg) {
        U4 pv = *(const U4*)(payg + s0 + m);
        c.p0 = pv.x; c.p1 = pv.y; c.p2 = pv.z; c.p3 = pv.w;
    } else {
        c.p0 = __float_as_uint(pm[(u32)(c.k0 & 0x1FFFFFull)]);
        if (m + 1 < cnt) c.p1 = __float_as_uint(pm[(u32)(c.k1 & 0x1FFFFFull)]);
        if (m + 2 < cnt) c.p2 = __float_as_uint(pm[(u32)(c.k2 & 0x1FFFFFull)]);
        if (m + 3 < cnt) c.p3 = __float_as_uint(pm[(u32)(c.k3 & 0x1FFFFFull)]);
    }
    if (m + 1 >= cnt) c.k1 = ~0ull;
    if (m + 2 >= cnt) c.k2 = ~0ull;
    if (m + 3 >= cnt) c.k3 = ~0ull;
}

template<int SI>
__device__ __forceinline__ void emit_body(
    const float* __restrict__ pm, const u32* __restrict__ payload,
    const u32* __restrict__ startsM, const ull* __restrict__ keys,
    const u32* __restrict__ segid, float* __restrict__ batch, int bb,
    float (&tile)[64][101], ull (&lkAll)[4][LKELEMS],
    u32 (&s_s0)[64], u32 (&s_cnt)[64], u32 (&s_seg)[64],
    u32 (&ovfl)[64], u32& ovflN)
{
    constexpr int WB   = 9 - SI;
    constexpr int G    = (SI == 0) ? 4 : (SI == 1) ? 16 : 64;    // lanes per cell
    constexpr int CAP  = G * 4;
    constexpr int STRD = (SI == 0) ? 18 : (SI == 1) ? 66 : 256;
    constexpr int NG   = 64 / G;
    constexpr int ROUNDS = 64 / (4 * NG);
    const int HW = 1 << (2 * WB);

    int t = threadIdx.x, wave = t >> 6, lane = t & 63;
    int gi = lane / G, li = lane % G;
    ull* lk = &lkAll[wave][0];

    if (t == 0) ovflN = 0;
    if (t < 64) {
        int cell = bb * 64 + t;
        u32 ci = (u32)cell >> WB, cj = (u32)cell & ((1u << WB) - 1u);
        u32 mb = morton2(ci, cj) << (2 * SI);
        u32 s0 = startsM[mb];
        s_s0[t]  = s0;
        s_cnt[t] = startsM[mb + (1u << (2 * SI))] - s0;
        s_seg[t] = segid[cell];
    }
    __syncthreads();

    CellRegs cur, nxt;
    {
        int lc0 = wave * NG + gi;
        loadCellG<CAP>(keys, payload, pm, s_s0[lc0], s_cnt[lc0], (u32)li, cur);
    }
#pragma unroll
    for (int rnd = 0; rnd < ROUNDS; ++rnd) {
        int lc = (rnd * 4 + wave) * NG + gi;
        u32 cnt = s_cnt[lc], m = (u32)li * 4u;
        bool fits = (cnt <= (u32)CAP);
        if (fits && m < cnt) {
            ull* dst = lk + gi * STRD + m;
            dst[0] = cur.k0; dst[1] = cur.k1; dst[2] = cur.k2; dst[3] = cur.k3;
        }
        if (!fits && li == 0) {
            u32 ix = atomicAdd(&ovflN, 1u);
            ovfl[ix] = (u32)lc;
        }
        if (rnd + 1 < ROUNDS) {
            int lc2 = ((rnd + 1) * 4 + wave) * NG + gi;
            loadCellG<CAP>(keys, payload, pm, s_s0[lc2], s_cnt[lc2], (u32)li, nxt);
        }
        if (cnt && fits) {
            asm volatile("s_waitcnt lgkmcnt(0)" ::: "memory");
            u32 cntR = (cnt + 3u) & ~3u;
            u32 r0 = 0, r1 = 0, r2 = 0, r3 = 0;
            const ull* kb = lk + gi * STRD;
            for (u32 j = 0; j < cntR; j += 4) {
                U2 a  = *(const U2*)(kb + j);
                U2 b2 = *(const U2*)(kb + j + 2);
                r0 += (a.x < cur.k0) + (a.y < cur.k0) + (b2.x < cur.k0) + (b2.y < cur.k0);
                r1 += (a.x < cur.k1) + (a.y < cur.k1) + (b2.x < cur.k1) + (b2.y < cur.k1);
                r2 += (a.x < cur.k2) + (a.y < cur.k2) + (b2.x < cur.k2) + (b2.y < cur.k2);
                r3 += (a.x < cur.k3) + (a.y < cur.k3) + (b2.x < cur.k3) + (b2.y < cur.k3);
            }
            if (m < cnt) {
                if (r0 < MAX_RAY)                 tile[lc][r0] = __uint_as_float(cur.p0);
                if (m + 1 < cnt && r1 < MAX_RAY)  tile[lc][r1] = __uint_as_float(cur.p1);
                if (m + 2 < cnt && r2 < MAX_RAY)  tile[lc][r2] = __uint_as_float(cur.p2);
                if (m + 3 < cnt && r3 < MAX_RAY)  tile[lc][r3] = __uint_as_float(cur.p3);
            }
        }
        cur = nxt;
    }
    __syncthreads();

    u32 no = ovflN;
    if (no && wave == 0) {
        for (u32 o = 0; o < no; ++o) {
            int lc = (int)ovfl[o];
            u32 s0 = s_s0[lc], cnt = s_cnt[lc];
            for (u32 i = lane; i < cnt; i += 64) {
                ull mk = keys[s0 + i];
                u32 r = 0;
                for (u32 j = 0; j < cnt; ++j) r += (keys[s0 + j] < mk) ? 1u : 0u;
                if (r < MAX_RAY) {
                    u32 pv = payload ? payload[s0 + i]
                                     : __float_as_uint(pm[(u32)(mk & 0x1FFFFFull)]);
                    tile[lc][r] = __uint_as_float(pv);
                }
            }
        }
    }
    __syncthreads();

    u32 myCnt = s_cnt[lane], mySeg = s_seg[lane];
    u32 lim = myCnt < MAX_RAY ? myCnt : MAX_RAY;
    for (int r = wave; r < MAX_RAY; r += 4) {
        if (myCnt) batch[(size_t)r * (size_t)HW + mySeg] = (r < (int)lim) ? tile[lane][r] : 0.0f;
    }
}

struct EmitArgs {
    const u32* segid[3]; float* batch[3]; float* lens[3]; float* canvas[3];
};
__global__ __launch_bounds__(256)
void emit_kernel(const float* __restrict__ pm,
                 const u32* __restrict__ payload,
                 const u32* __restrict__ startsM,
                 const ull* __restrict__ keys,
                 EmitArgs ea,
                 const u32* __restrict__ ncells) {
    __shared__ float tile[64][101];
    __shared__ __align__(16) ull lkAll[4][LKELEMS];
    __shared__ u32 s_s0[64], s_cnt[64], s_seg[64], ovfl[64], ovflN;

    int b = blockIdx.x;
    if (b >= 5376) {                       // fused tail-zero blocks
        int tb = b - 5376, t = threadIdx.x;
        for (int si = 0; si < 3; ++si) {
            int HW = (si == 0) ? 262144 : (si == 1) ? 65536 : 16384;
            float* batch = ea.batch[si];
            float* lens = ea.lens[si];
            float* canv = ea.canvas[si];
            u32 nc = ncells[si];
            for (u32 col = nc + (u32)(tb * 256 + t); col < (u32)HW; col += NTAIL * 256) {
                lens[col] = 0.0f;
                canv[2 * col] = 0.0f; canv[2 * col + 1] = 0.0f;
                for (int r = 0; r < MAX_RAY; ++r)
                    batch[(size_t)r * (size_t)HW + col] = 0.0f;
            }
        }
        return;
    }
    if (b < 256)
        emit_body<2>(pm, payload, startsM, keys, ea.segid[2], ea.batch[2], b,
                     tile, lkAll, s_s0, s_cnt, s_seg, ovfl, ovflN);
    else if (b < 1280)
        emit_body<1>(pm, payload, startsM, keys, ea.segid[1], ea.batch[1], b - 256,
                     tile, lkAll, s_s0, s_cnt, s_seg, ovfl, ovflN);
    else
        emit_body<0>(pm, payload, startsM, keys, ea.segid[0], ea.batch[0], b - 1280,
                     tile, lkAll, s_s0, s_cnt, s_seg, ovfl, ovflN);
}

extern "C" void kernel_launch(void* const* d_in, const int* in_sizes, int n_in,
                              void* d_out, int out_size, void* d_ws, size_t ws_size,
                              hipStream_t stream) {
    const float2* coords = (const float2*)d_in[0];
    const float*  depth  = (const float*)d_in[1];
    const float*  pm     = (const float*)d_in[2];
    float* out = (float*)d_out;
    const int n = in_sizes[1];

    const int HWs[3] = {512 * 512, 256 * 256, 128 * 128};

    // ---- workspace layout ----
    char* ws = (char*)d_ws;
    size_t off = 0;
    ull* keysF   = (ull*)(ws + off); off += (size_t)n * 8;
    u32* countsM = (u32*)(ws + off); off += (size_t)N0 * 4;
    u32* startsM = (u32*)(ws + off); off += (size_t)(N0 + 64) * 4;
    u32* segid[3];
    for (int i = 0; i < 3; ++i) { segid[i] = (u32*)(ws + off); off += (size_t)HWs[i] * 4; }
    u32* bsumB = (u32*)(ws + off); off += 2048 * 4;
    u32* bucketCnt   = (u32*)(ws + off); off += NBUCK * 4;
    u32* bucketStart = (u32*)(ws + off); off += (NBUCK + 64) * 4;
    u32* bucketCur   = (u32*)(ws + off); off += NBUCK * 4;
    u32* ncells      = (u32*)(ws + off); off += 64 * 4;
    u32* payF        = (u32*)(ws + off);
    size_t needPay = off + (size_t)n * 4;
    size_t offStage = needPay;
    ull* stageK = (ull*)(ws + offStage);
    u32* stageP = (u32*)(ws + offStage + (size_t)NBUCK * CAPB * 8);
    size_t needStaged = offStage + (size_t)NBUCK * CAPB * 12;

    bool haveStage = (ws_size >= needStaged);
    u32* payg = (ws_size >= needPay) ? payF : nullptr;

    // ---- output offsets ----
    size_t offB[3], offL[3], offC[3];
    size_t o = 0;
    for (int i = 0; i < 3; ++i) { offB[i] = o; o += (size_t)MAX_RAY * HWs[i]; }
    for (int i = 0; i < 3; ++i) { offL[i] = o; o += (size_t)HWs[i]; }
    for (int i = 0; i < 3; ++i) { offC[i] = o; o += 2 * (size_t)HWs[i]; }

    hipMemsetAsync(bucketCnt, 0, NBUCK * 4, stream);

    const int nblkPts = (n + PTS_PER_BLK - 1) / PTS_PER_BLK;

    if (haveStage) {
        bucket_scatter_fixed<<<nblkPts, 256, 0, stream>>>(coords, depth, pm, bucketCnt,
                                                          stageK, stageP, n);
        place_fused2<<<NBUCK, 256, 0, stream>>>(stageK, stageP, bucketCnt,
                                                startsM, keysF, payF);
        payg = payF;
    } else {
        bucket_hist_kernel<<<nblkPts, 256, 0, stream>>>(coords, bucketCnt, n);
        bucket_scan_kernel<<<1, NBUCK, 0, stream>>>(bucketCnt, bucketStart, bucketCur, n);
        bucket_scatter_kernel<<<nblkPts, 256, 0, stream>>>(coords, depth, pm, bucketCur,
                                                           keysF, payg, n);
        cell_hist_kernel<<<NBUCK, 256, 0, stream>>>(keysF, bucketStart, countsM);
        scanA_final2<<<NBLK0, 256, 0, stream>>>(countsM, bucketStart, startsM);
        place_kernel<<<NBUCK, 256, 0, stream>>>(keysF, payg, bucketStart, startsM);
    }

    SegArgs sa;
    for (int i = 0; i < 3; ++i) {
        sa.segid[i]  = segid[i];
        sa.lens[i]   = out + offL[i];
        sa.canvas[i] = out + offC[i];
    }
    scanB_partial<<<NBLKB2, 256, 0, stream>>>(startsM, bsumB);
    scanB_final<<<NBLKB2, 256, 0, stream>>>(startsM, bsumB, sa, ncells);

    EmitArgs ea;
    for (int i = 0; i < 3; ++i) {
        ea.segid[i]  = segid[i];
        ea.batch[i]  = out + offB[i];
        ea.lens[i]   = out + offL[i];
        ea.canvas[i] = out + offC[i];
    }
    emit_kernel<<<5376 + NTAIL, 256, 0, stream>>>(pm, payg, startsM, keysF, ea, ncells);
}